// Round 1
// 442.146 us; speedup vs baseline: 1.1556x; 1.1556x over previous
//
#include <hip/hip_runtime.h>

typedef unsigned short u16;
typedef unsigned int u32;
typedef unsigned long long u64;
typedef __attribute__((ext_vector_type(8))) __bf16 bf16x8;
typedef __attribute__((ext_vector_type(4))) float f32x4;

constexpr int Bn = 1024, Dn = 2048, Pn = 16384, Cn = 8192, Kp = 8;
constexpr float INV_TEMP = 20.0f;
constexpr int KNN = 50;
constexpr float NEGV = -1e4f;

__device__ __forceinline__ u16 f32_to_bf16_bits(float f) {
  const u32 u = __float_as_uint(f);
  return (u16)((u + 0x7FFFu + ((u >> 16) & 1u)) >> 16);  // RNE; exact if f already bf16-rounded
}

// ---------- async global->LDS, 16B per lane (wave-uniform LDS base) ----------
__device__ __forceinline__ void async_copy16(const void* g, void* l) {
  __builtin_amdgcn_global_load_lds(
      (__attribute__((address_space(1))) void*)(g),
      (__attribute__((address_space(3))) void*)(l), 16, 0, 0);
}

// ---------- block reductions (256 threads, 4 waves) ----------
__device__ __forceinline__ float blk_max(float v, float* red) {
#pragma unroll
  for (int off = 32; off > 0; off >>= 1) v = fmaxf(v, __shfl_xor(v, off));
  if ((threadIdx.x & 63) == 0) red[threadIdx.x >> 6] = v;
  __syncthreads();
  float r = fmaxf(fmaxf(red[0], red[1]), fmaxf(red[2], red[3]));
  __syncthreads();
  return r;
}
__device__ __forceinline__ float blk_sum(float v, float* red) {
#pragma unroll
  for (int off = 32; off > 0; off >>= 1) v += __shfl_xor(v, off);
  if ((threadIdx.x & 63) == 0) red[threadIdx.x >> 6] = v;
  __syncthreads();
  float r = red[0] + red[1] + red[2] + red[3];
  __syncthreads();
  return r;
}
__device__ __forceinline__ int blk_sum_i(int v, int* red) {
#pragma unroll
  for (int off = 32; off > 0; off >>= 1) v += __shfl_xor(v, off);
  if ((threadIdx.x & 63) == 0) red[threadIdx.x >> 6] = v;
  __syncthreads();
  int r = red[0] + red[1] + red[2] + red[3];
  __syncthreads();
  return r;
}

// ---------- dtype sniff: fp32 (flag=0) or bf16 (flag=1)? ----------
__global__ __launch_bounds__(256) void sniff(const void* __restrict__ A,
                                             int* __restrict__ flag) {
  __shared__ float redf[4];
  const int tid = threadIdx.x;
  const float* af = (const float*)A;
  const u16* ab = (const u16*)A;
  float s2 = 0.f, s2b = 0.f;
  for (int i = tid; i < Dn; i += 256) {
    const float x = af[i];
    s2 += x * x;
    const float y = __uint_as_float(((u32)ab[i]) << 16);
    s2b += y * y;
  }
  s2 = blk_sum(s2, redf);
  s2b = blk_sum(s2b, redf);
  if (tid == 0) flag[0] = (fabsf(s2b - 1.f) < fabsf(s2 - 1.f)) ? 1 : 0;
}

// ---------- fp32 (or bf16) -> packed bf16, 8 elements per thread-iter -------
__global__ __launch_bounds__(256) void to_bf16(
    const void* __restrict__ src, u16* __restrict__ dst, int n8,
    const int* __restrict__ flag) {
  const bool isBf16 = (*flag != 0);
  int i = blockIdx.x * 256 + threadIdx.x;
  const int stride = gridDim.x * 256;
  for (; i < n8; i += stride) {
    if (isBf16) {
      ((ulonglong2*)dst)[i] = ((const ulonglong2*)src)[i];
    } else {
      const float4 a = ((const float4*)src)[2 * i];
      const float4 b = ((const float4*)src)[2 * i + 1];
      ushort4 p, q;
      p.x = f32_to_bf16_bits(a.x); p.y = f32_to_bf16_bits(a.y);
      p.z = f32_to_bf16_bits(a.z); p.w = f32_to_bf16_bits(a.w);
      q.x = f32_to_bf16_bits(b.x); q.y = f32_to_bf16_bits(b.y);
      q.z = f32_to_bf16_bits(b.z); q.w = f32_to_bf16_bits(b.w);
      ((ushort4*)dst)[2 * i] = p;
      ((ushort4*)dst)[2 * i + 1] = q;
    }
  }
}

// ---------- v2 GEMM: C[M,N] = scale * A[M,K] . B[N,K]^T, bf16 in / f32 out --
// BM x 256 tile, BK=64, 512 thr / 8 waves (2x4), double-buffered LDS,
// counted vmcnt (T4), XOR-swizzled LDS via pre-swizzled global source (T2),
// setprio around MFMA cluster (T5). Accumulation order identical to m97
// (16x16x32 bf16, increasing K) -> bit-exact same scores.
//
// Swizzle: 16B-unit u_phys = u_log ^ (row & 7). global_load_lds dest stays
// linear; lane's global SOURCE is permuted; fragment ds_read applies the
// same involution. Balanced 8 accesses/bank on ds_read_b128 (the floor).
template <int BM>
__global__ __launch_bounds__(512, 2) void gemm_bt_v2(
    const u16* __restrict__ A, const u16* __restrict__ Bm,
    float* __restrict__ C, int N, int K, float scale)
{
  constexpr int IM = BM / 32;    // A-frags per wave (BM/2 rows / 16)
  constexpr int LA = BM / 64;    // A block-loads per K-tile (512 lanes x 16B each)
  constexpr int LB = 4;          // B block-loads per K-tile (256 rows)
  __shared__ __align__(16) u16 smem[2][(BM + 256) * 64];  // [buf][A | B]

  const int tid  = threadIdx.x;
  const int lane = tid & 63;
  const int wave = tid >> 6;
  const int wm   = wave >> 2;    // 0..1  row-half
  const int wn   = wave & 3;     // 0..3  col-quarter
  const int quad = lane >> 4;
  const int r16  = lane & 15;
  const int tileM = blockIdx.y * BM;
  const int tileN = blockIdx.x * 256;

  // per-lane staging source pointers (pre-swizzled), point at next tile to stage
  const u16* pA[LA];
  const u16* pB[LB];
#pragma unroll
  for (int ld = 0; ld < LA; ++ld) {
    const int pu  = ld * 512 + wave * 64 + lane;   // 16B unit within A tile
    const int row = pu >> 3;
    const int ul  = (pu & 7) ^ (row & 7);          // logical k-group at this phys slot
    pA[ld] = A + (size_t)(tileM + row) * K + ul * 8;
  }
#pragma unroll
  for (int ld = 0; ld < LB; ++ld) {
    const int pu  = ld * 512 + wave * 64 + lane;
    const int row = pu >> 3;
    const int ul  = (pu & 7) ^ (row & 7);
    pB[ld] = Bm + (size_t)(tileN + row) * K + ul * 8;
  }

  // fragment read byte offsets (involution applied on read side)
  const int physOff0 = ((quad)     ^ (r16 & 7)) * 16;  // kk=0: u_log = quad
  const int physOff1 = ((4 + quad) ^ (r16 & 7)) * 16;  // kk=1: u_log = 4+quad
  const int baseA = (wm * (BM / 2) + r16) * 128;       // byte offset in A region
  const int baseB = (wn * 64 + r16) * 128;             // byte offset in B region

  f32x4 acc[IM][4] = {};

  const int NT = K / 64;

  auto stage = [&](int buf) {
    u16* base = &smem[buf][0];
#pragma unroll
    for (int ld = 0; ld < LA; ++ld) {
      async_copy16(pA[ld], base + (size_t)(ld * 512 + wave * 64) * 8);
      pA[ld] += 64;
    }
#pragma unroll
    for (int ld = 0; ld < LB; ++ld) {
      async_copy16(pB[ld], base + (size_t)BM * 64 + (size_t)(ld * 512 + wave * 64) * 8);
      pB[ld] += 64;
    }
  };

  stage(0);   // tile 0 -> buf 0
  stage(1);   // tile 1 -> buf 1

  for (int t = 0; t < NT; ++t) {
    const int b = t & 1;
    // wait for OWN tile-t loads (t+1's stay in flight), then sync all waves.
    if (t == NT - 1) {
      asm volatile("s_waitcnt vmcnt(0)\n\ts_barrier" ::: "memory");
    } else if constexpr (BM == 256) {
      asm volatile("s_waitcnt vmcnt(8)\n\ts_barrier" ::: "memory");
    } else {
      asm volatile("s_waitcnt vmcnt(6)\n\ts_barrier" ::: "memory");
    }

    const char* bufA = (const char*)&smem[b][0];
    const char* bufB = bufA + (size_t)BM * 128;

    bf16x8 bfr[4][2], afr[IM][2];
#pragma unroll
    for (int j = 0; j < 4; ++j) {
      bfr[j][0] = *(const bf16x8*)(bufB + baseB + j * 2048 + physOff0);
      bfr[j][1] = *(const bf16x8*)(bufB + baseB + j * 2048 + physOff1);
    }
#pragma unroll
    for (int i = 0; i < IM; ++i) {
      afr[i][0] = *(const bf16x8*)(bufA + baseA + i * 2048 + physOff0);
      afr[i][1] = *(const bf16x8*)(bufA + baseA + i * 2048 + physOff1);
    }
    // all waves done reading buf b -> safe to overwrite with tile t+2
    asm volatile("s_waitcnt lgkmcnt(0)\n\ts_barrier" ::: "memory");
    if (t + 2 < NT) stage(b);

    __builtin_amdgcn_s_setprio(1);
#pragma unroll
    for (int i = 0; i < IM; ++i)
#pragma unroll
      for (int j = 0; j < 4; ++j) {
        acc[i][j] = __builtin_amdgcn_mfma_f32_16x16x32_bf16(afr[i][0], bfr[j][0], acc[i][j], 0, 0, 0);
        acc[i][j] = __builtin_amdgcn_mfma_f32_16x16x32_bf16(afr[i][1], bfr[j][1], acc[i][j], 0, 0, 0);
      }
    __builtin_amdgcn_s_setprio(0);
  }

  // C/D layout (verified m89/m91): col = lane&15, row = quad*4 + reg
#pragma unroll
  for (int i = 0; i < IM; ++i)
#pragma unroll
    for (int j = 0; j < 4; ++j) {
      const int ccol = tileN + wn * 64 + j * 16 + r16;
#pragma unroll
      for (int rg = 0; rg < 4; ++rg) {
        const int rrow = tileM + wm * (BM / 2) + i * 16 + quad * 4 + rg;
        C[(size_t)rrow * N + ccol] = scale * acc[i][j][rg];
      }
    }
}

// ---------- fallback GEMM (small ws): manual staging, runtime dtype ----------
__global__ __launch_bounds__(256) void gemm_bt_f32(
    const void* __restrict__ Av, const void* __restrict__ Bv,
    const int* __restrict__ flag, float* __restrict__ C,
    int N, int K, float scale)
{
  __shared__ __align__(16) u16 As[128 * 32];
  __shared__ __align__(16) u16 Bs[128 * 32];
  const int tid  = threadIdx.x;
  const int lane = tid & 63;
  const int wave = tid >> 6;
  const int tileM = blockIdx.y * 128;
  const int tileN = blockIdx.x * 128;
  const int wm = (wave & 1) * 64;
  const int wn = (wave >> 1) * 64;
  const int quad = lane >> 4;
  const int r16  = lane & 15;
  const bool isBf16 = (*flag != 0);

  f32x4 acc[4][4] = {};

  for (int k0 = 0; k0 < K; k0 += 32) {
#pragma unroll
    for (int r = 0; r < 4; ++r) {
      const int idx = tid + 256 * r;
      const int row = idx >> 3;
      const int c   = (idx & 7) * 4;
      u16* da = &As[row * 32 + c];
      u16* db = &Bs[row * 32 + c];
      if (isBf16) {
        const u16* a16 = (const u16*)Av;
        const u16* b16 = (const u16*)Bv;
        *(ushort4*)da = *(const ushort4*)(a16 + (size_t)(tileM + row) * K + k0 + c);
        *(ushort4*)db = *(const ushort4*)(b16 + (size_t)(tileN + row) * K + k0 + c);
      } else {
        const float* a32 = (const float*)Av;
        const float* b32 = (const float*)Bv;
        const float4 va = *(const float4*)(a32 + (size_t)(tileM + row) * K + k0 + c);
        const float4 vb = *(const float4*)(b32 + (size_t)(tileN + row) * K + k0 + c);
        ushort4 pa, pb;
        pa.x = f32_to_bf16_bits(va.x); pa.y = f32_to_bf16_bits(va.y);
        pa.z = f32_to_bf16_bits(va.z); pa.w = f32_to_bf16_bits(va.w);
        pb.x = f32_to_bf16_bits(vb.x); pb.y = f32_to_bf16_bits(vb.y);
        pb.z = f32_to_bf16_bits(vb.z); pb.w = f32_to_bf16_bits(vb.w);
        *(ushort4*)da = pa;
        *(ushort4*)db = pb;
      }
    }
    __syncthreads();
    bf16x8 af[4], bfr[4];
#pragma unroll
    for (int i = 0; i < 4; ++i)
      af[i] = *(const bf16x8*)&As[(wm + i * 16 + r16) * 32 + quad * 8];
#pragma unroll
    for (int j = 0; j < 4; ++j)
      bfr[j] = *(const bf16x8*)&Bs[(wn + j * 16 + r16) * 32 + quad * 8];
#pragma unroll
    for (int i = 0; i < 4; ++i)
#pragma unroll
      for (int j = 0; j < 4; ++j)
        acc[i][j] = __builtin_amdgcn_mfma_f32_16x16x32_bf16(af[i], bfr[j], acc[i][j], 0, 0, 0);
    __syncthreads();
  }

#pragma unroll
  for (int i = 0; i < 4; ++i)
#pragma unroll
    for (int j = 0; j < 4; ++j) {
      const int ccol = tileN + wn + j * 16 + r16;
#pragma unroll
      for (int rg = 0; rg < 4; ++rg) {
        const int rrow = tileM + wm + i * 16 + quad * 4 + rg;
        C[(size_t)rrow * N + ccol] = scale * acc[i][j][rg];
      }
    }
}

// ---------- per-row class CE: lse(row) - row[class], float4 loads ----------
__global__ __launch_bounds__(256) void class_row(
    const float* __restrict__ scores, const int* __restrict__ classes,
    float* __restrict__ rlc)
{
  __shared__ float redf[4];
  const int b = blockIdx.x;
  const int tid = threadIdx.x;
  const float* row = scores + (size_t)b * Cn;
  float4 v[Cn / 1024];
#pragma unroll
  for (int s = 0; s < Cn / 1024; ++s)
    v[s] = *(const float4*)(row + s * 1024 + tid * 4);
  float m = -3.0e38f;
#pragma unroll
  for (int s = 0; s < Cn / 1024; ++s)
    m = fmaxf(m, fmaxf(fmaxf(v[s].x, v[s].y), fmaxf(v[s].z, v[s].w)));
  m = blk_max(m, redf);
  float sum = 0.f;
#pragma unroll
  for (int s = 0; s < Cn / 1024; ++s)
    sum += expf(v[s].x - m) + expf(v[s].y - m) + expf(v[s].z - m) + expf(v[s].w - m);
  sum = blk_sum(sum, redf);
  if (tid == 0) {
    const int cls = classes[b];
    rlc[b] = m + logf(sum) - row[cls];
  }
}

// ---------- per-row proxy loss: exact top-50 via key binary search ----------
__global__ __launch_bounds__(256) void proxy_row(
    const float* __restrict__ scores, const int* __restrict__ l2p,
    const int* __restrict__ labels, float* __restrict__ rlp)
{
  __shared__ float redf[4];
  __shared__ int redi[4];
  __shared__ int posIdx[Kp];
  __shared__ float posVal[Kp];
  const int b = blockIdx.x;
  const int tid = threadIdx.x;
  const float* row = scores + (size_t)b * Pn;

  if (tid < Kp) {
    const int lbl = labels[b];
    const int p = l2p[lbl * Kp + tid];
    posIdx[tid] = p;
    posVal[tid] = (p >= 0) ? row[p] : NEGV;   // gather BEFORE masking
  }
  __syncthreads();

  u64 excl = 0ull;
#pragma unroll
  for (int k = 0; k < Kp; ++k) {
    const int p = posIdx[k];
    if (p >= 0 && ((p >> 2) & 255) == tid)
      excl |= (1ull << (((p >> 10) << 2) | (p & 3)));
  }

  u32 key[Pn / 256];
  float vmax = -3.0e38f;
#pragma unroll
  for (int s = 0; s < Pn / 1024; ++s) {
    const float4 v4 = *(const float4*)(row + s * 1024 + tid * 4);
    const float vv[4] = {v4.x, v4.y, v4.z, v4.w};
#pragma unroll
    for (int j = 0; j < 4; ++j) {
      const float v = vv[j];
      const u32 bits = __float_as_uint(v);
      const u32 k = (bits & 0x80000000u) ? ~bits : (bits ^ 0x80000000u);
      const bool ex = (excl >> (s * 4 + j)) & 1ull;
      key[s * 4 + j] = ex ? 0u : k;            // key 0 = never selected
      if (!ex) vmax = fmaxf(vmax, v);
    }
  }
  float M = blk_max(vmax, redf);
#pragma unroll
  for (int k = 0; k < Kp; ++k) M = fmaxf(M, posVal[k]);

  // largest T with count(key >= T) >= 50  ->  T = 50th largest key
  u32 lo = 0;
  for (int bit = 31; bit >= 0; --bit) {
    const u32 cand = lo | (1u << bit);
    int c = 0;
#pragma unroll
    for (int s = 0; s < Pn / 256; ++s) c += (key[s] >= cand) ? 1 : 0;
    c = blk_sum_i(c, redi);
    if (c >= KNN) lo = cand;
  }

  int cgt = 0; float s1 = 0.f;
#pragma unroll
  for (int s = 0; s < Pn / 256; ++s) {
    if (key[s] > lo) {
      ++cgt;
      const u32 kk = key[s];
      const u32 bits = (kk & 0x80000000u) ? (kk ^ 0x80000000u) : ~kk;
      s1 += expf(__uint_as_float(bits) - M);
    }
  }
  cgt = blk_sum_i(cgt, redi);
  s1 = blk_sum(s1, redf);

  if (tid == 0) {
    const u32 tb = (lo & 0x80000000u) ? (lo ^ 0x80000000u) : ~lo;
    const float tv = __uint_as_float(tb);
    const float Sneg = s1 + (float)(KNN - cgt) * expf(tv - M);
    float Spos = 0.f, sp = 0.f; int nv = 0;
#pragma unroll
    for (int k = 0; k < Kp; ++k) {
      Spos += expf(posVal[k] - M);
      if (posIdx[k] >= 0) { sp += posVal[k]; ++nv; }
    }
    float loss = 0.f;
    if (nv > 0) loss = M + logf(Spos + Sneg) - sp / (float)nv;
    rlp[b] = loss;
  }
}

// ---------- final: mean over batch, fp32 store ----------
__global__ __launch_bounds__(256) void final_reduce(
    const float* __restrict__ rlp, const float* __restrict__ rlc,
    float* __restrict__ out)
{
  __shared__ float redf[4];
  const int tid = threadIdx.x;
  float acc = 0.f;
  for (int i = tid; i < Bn; i += 256) acc += rlp[i] + rlc[i];
  acc = blk_sum(acc, redf);
  if (tid == 0) out[0] = acc * (1.0f / (float)Bn);
}

extern "C" void kernel_launch(void* const* d_in, const int* in_sizes, int n_in,
                              void* d_out, int out_size, void* d_ws, size_t ws_size,
                              hipStream_t stream) {
  const void* inputs  = d_in[0];              // [B,D]  float (fp32-holding-bf16 or bf16)
  const void* pcent   = d_in[1];              // [P,D]
  const void* ccent   = d_in[2];              // [C,D]
  const int* l2p      = (const int*)d_in[3];  // [C,K]
  const int* labels   = (const int*)d_in[5];  // [B]
  const int* classes  = (const int*)d_in[6];  // [B]

  char* ws = (char*)d_ws;
  float* scores = (float*)ws;                                  // 64 MB
  size_t off = (size_t)64 * 1024 * 1024;
  float* rlc = (float*)(ws + off);  off += Bn * 4;
  float* rlp = (float*)(ws + off);  off += Bn * 4;
  int* flag  = (int*)(ws + off);    off += 4096;               // pad
  u16* Abf   = (u16*)(ws + off);    off += (size_t)Bn * Dn * 2;
  u16* Cbf   = (u16*)(ws + off);    off += (size_t)Cn * Dn * 2;
  u16* Pbf   = (u16*)(ws + off);    off += (size_t)Pn * Dn * 2;
  const bool big = (ws_size >= off);          // constant per-run -> graph-safe

  sniff<<<1, 256, 0, stream>>>(inputs, flag);

  if (big) {
    to_bf16<<<1024, 256, 0, stream>>>(inputs, Abf, Bn * Dn / 8, flag);
    to_bf16<<<2048, 256, 0, stream>>>(ccent, Cbf, Cn * Dn / 8, flag);
    to_bf16<<<4096, 256, 0, stream>>>(pcent, Pbf, Pn * Dn / 8, flag);

    // class GEMM: BM=128 -> grid 32x8 = 256 blocks (was 128, half-idle chip)
    gemm_bt_v2<128><<<dim3(Cn / 256, Bn / 128), 512, 0, stream>>>(
        Abf, Cbf, scores, Cn, Dn, INV_TEMP);
    class_row<<<Bn, 256, 0, stream>>>(scores, classes, rlc);

    // proxy GEMM: BM=256 -> grid 64x4 = 256 blocks, 1/CU
    gemm_bt_v2<256><<<dim3(Pn / 256, Bn / 256), 512, 0, stream>>>(
        Abf, Pbf, scores, Pn, Dn, INV_TEMP);
    proxy_row<<<Bn, 256, 0, stream>>>(scores, l2p, labels, rlp);
  } else {
    gemm_bt_f32<<<dim3(Cn / 128, Bn / 128), 256, 0, stream>>>(
        inputs, ccent, flag, scores, Cn, Dn, INV_TEMP);
    class_row<<<Bn, 256, 0, stream>>>(scores, classes, rlc);

    gemm_bt_f32<<<dim3(Pn / 128, Bn / 128), 256, 0, stream>>>(
        inputs, pcent, flag, scores, Pn, Dn, INV_TEMP);
    proxy_row<<<Bn, 256, 0, stream>>>(scores, l2p, labels, rlp);
  }

  final_reduce<<<1, 256, 0, stream>>>(rlp, rlc, (float*)d_out);
}

// Round 2
// 432.329 us; speedup vs baseline: 1.1818x; 1.0227x over previous
//
#include <hip/hip_runtime.h>

typedef unsigned short u16;
typedef unsigned int u32;
typedef unsigned long long u64;
typedef __attribute__((ext_vector_type(8))) __bf16 bf16x8;
typedef __attribute__((ext_vector_type(4))) float f32x4;

constexpr int Bn = 1024, Dn = 2048, Pn = 16384, Cn = 8192, Kp = 8;
constexpr float INV_TEMP = 20.0f;
constexpr int KNN = 50;
constexpr float NEGV = -1e4f;

__device__ __forceinline__ u16 f32_to_bf16_bits(float f) {
  const u32 u = __float_as_uint(f);
  return (u16)((u + 0x7FFFu + ((u >> 16) & 1u)) >> 16);  // RNE; exact if f already bf16-rounded
}

// ---------- async global->LDS, 16B per lane (wave-uniform LDS base) ----------
__device__ __forceinline__ void async_copy16(const void* g, void* l) {
  __builtin_amdgcn_global_load_lds(
      (__attribute__((address_space(1))) void*)(g),
      (__attribute__((address_space(3))) void*)(l), 16, 0, 0);
}

// ---------- block reductions (256 threads, 4 waves) ----------
__device__ __forceinline__ float blk_max(float v, float* red) {
#pragma unroll
  for (int off = 32; off > 0; off >>= 1) v = fmaxf(v, __shfl_xor(v, off));
  if ((threadIdx.x & 63) == 0) red[threadIdx.x >> 6] = v;
  __syncthreads();
  float r = fmaxf(fmaxf(red[0], red[1]), fmaxf(red[2], red[3]));
  __syncthreads();
  return r;
}
__device__ __forceinline__ float blk_sum(float v, float* red) {
#pragma unroll
  for (int off = 32; off > 0; off >>= 1) v += __shfl_xor(v, off);
  if ((threadIdx.x & 63) == 0) red[threadIdx.x >> 6] = v;
  __syncthreads();
  float r = red[0] + red[1] + red[2] + red[3];
  __syncthreads();
  return r;
}
__device__ __forceinline__ int blk_sum_i(int v, int* red) {
#pragma unroll
  for (int off = 32; off > 0; off >>= 1) v += __shfl_xor(v, off);
  if ((threadIdx.x & 63) == 0) red[threadIdx.x >> 6] = v;
  __syncthreads();
  int r = red[0] + red[1] + red[2] + red[3];
  __syncthreads();
  return r;
}

// ---------- dtype sniff: fp32 (flag=0) or bf16 (flag=1)? ----------
__global__ __launch_bounds__(256) void sniff(const void* __restrict__ A,
                                             int* __restrict__ flag) {
  __shared__ float redf[4];
  const int tid = threadIdx.x;
  const float* af = (const float*)A;
  const u16* ab = (const u16*)A;
  float s2 = 0.f, s2b = 0.f;
  for (int i = tid; i < Dn; i += 256) {
    const float x = af[i];
    s2 += x * x;
    const float y = __uint_as_float(((u32)ab[i]) << 16);
    s2b += y * y;
  }
  s2 = blk_sum(s2, redf);
  s2b = blk_sum(s2b, redf);
  if (tid == 0) flag[0] = (fabsf(s2b - 1.f) < fabsf(s2 - 1.f)) ? 1 : 0;
}

// ---------- fused fp32 (or bf16) -> packed bf16 for all three matrices ------
__global__ __launch_bounds__(256) void to_bf16_all(
    const void* __restrict__ sa, const void* __restrict__ sc,
    const void* __restrict__ sp, u16* __restrict__ da, u16* __restrict__ dc,
    u16* __restrict__ dp, const int* __restrict__ flag) {
  constexpr int nA = Bn * Dn / 8, nC = Cn * Dn / 8, nP = Pn * Dn / 8;
  const bool isBf16 = (*flag != 0);
  int i = blockIdx.x * 256 + threadIdx.x;
  const int stride = gridDim.x * 256;
  for (; i < nA + nC + nP; i += stride) {
    const void* src; u16* dst; int j;
    if (i < nA)           { src = sa; dst = da; j = i; }
    else if (i < nA + nC) { src = sc; dst = dc; j = i - nA; }
    else                  { src = sp; dst = dp; j = i - nA - nC; }
    if (isBf16) {
      ((ulonglong2*)dst)[j] = ((const ulonglong2*)src)[j];
    } else {
      const float4 a = ((const float4*)src)[2 * j];
      const float4 b = ((const float4*)src)[2 * j + 1];
      ushort4 p, q;
      p.x = f32_to_bf16_bits(a.x); p.y = f32_to_bf16_bits(a.y);
      p.z = f32_to_bf16_bits(a.z); p.w = f32_to_bf16_bits(a.w);
      q.x = f32_to_bf16_bits(b.x); q.y = f32_to_bf16_bits(b.y);
      q.z = f32_to_bf16_bits(b.z); q.w = f32_to_bf16_bits(b.w);
      ((ushort4*)dst)[2 * j] = p;
      ((ushort4*)dst)[2 * j + 1] = q;
    }
  }
}

// ---------- v3 GEMM: C[M,N] = scale * A[M,K] . B[N,K]^T, bf16 in / f32 out --
// BM x 256 tile, BK=64, K=2048 hardcoded, 512 thr / 8 waves (2x4).
// Double-buffered LDS + counted vmcnt (T4) + XOR-swizzle via pre-swizzled
// global source (T2) + snake 4-phase quadrant interleave (T3) + setprio (T5).
// Quadrant order (A0xB01),(A0xB23),(A1xB23),(A1xB01): each phase's ds_reads
// hide under the previous phase's MFMAs via the compiler's precise lgkmcnt;
// only A1's reads drain at the buffer-reuse barrier; staging of tile t+2
// overlaps the last MFMA quadrant. Per-acc accumulation order (kk0,kk1 per
// K-tile, increasing t) is identical to v2 -> bit-exact same scores.
template <int BM>
__global__ __launch_bounds__(512, 2) void gemm_4ph(
    const u16* __restrict__ A, const u16* __restrict__ Bm,
    float* __restrict__ C, int N, float scale)
{
  constexpr int K  = 2048;
  constexpr int IM = BM / 32;    // A-frags per wave (8 or 4)
  constexpr int AH = IM / 2;     // A-frags per half
  constexpr int LA = BM / 64;    // A gloads per K-tile (4 or 2)
  constexpr int LB = 4;          // B gloads per K-tile
  constexpr int LT = LA + LB;    // loads per K-tile (8 or 6)
  constexpr int NT = K / 64;     // 32 K-tiles
  __shared__ __align__(16) u16 smem[2][(BM + 256) * 64];

  const int tid  = threadIdx.x;
  const int lane = tid & 63;
  const int wave = tid >> 6;
  const int wm   = wave >> 2;    // 0..1  row-half
  const int wn   = wave & 3;     // 0..3  col-quarter
  const int quad = lane >> 4;
  const int r16  = lane & 15;
  const int tileM = blockIdx.y * BM;
  const int tileN = blockIdx.x * 256;

  // pre-swizzled per-lane source offsets (16B-unit u_phys = u_log ^ (row&7));
  // rows step by 64 per ld slot -> (row&7) invariant -> single base offset.
  const int pu   = wave * 64 + lane;     // 16B unit 0..511
  const int row0 = pu >> 3;              // 0..63
  const int ul0  = (pu & 7) ^ (row0 & 7);
  const u32 offA0 = (u32)(tileM + row0) * K + ul0 * 8;
  const u32 offB0 = (u32)(tileN + row0) * K + ul0 * 8;

  auto stage = [&](int t, int buf) {
    u16* base = &smem[buf][0];
    const u32 ko = (u32)t * 64;
#pragma unroll
    for (int ld = 0; ld < LA; ++ld)
      async_copy16(A + offA0 + (u32)ld * (64 * K) + ko,
                   base + (ld * 512 + wave * 64) * 8);
#pragma unroll
    for (int ld = 0; ld < LB; ++ld)
      async_copy16(Bm + offB0 + (u32)ld * (64 * K) + ko,
                   base + BM * 64 + (ld * 512 + wave * 64) * 8);
  };

  // fragment LDS byte offsets (read-side swizzle, same involution)
  const int pOff0 = ((0 + quad) ^ (r16 & 7)) * 16;   // kk=0
  const int pOff1 = ((4 + quad) ^ (r16 & 7)) * 16;   // kk=1
  const int baseA = (wm * (BM / 2) + r16) * 128;
  const int baseB = (wn * 64 + r16) * 128;

  f32x4 acc[IM][4] = {};

  stage(0, 0);
  stage(1, 1);

  for (int t = 0; t < NT; ++t) {
    const int b = t & 1;
    // tile-t's LDS writes done (t+1's LT loads may stay in flight)
    if (t == NT - 1) {
      asm volatile("s_waitcnt vmcnt(0)\n\ts_barrier" ::: "memory");
    } else if constexpr (LT == 8) {
      asm volatile("s_waitcnt vmcnt(8)\n\ts_barrier" ::: "memory");
    } else {
      asm volatile("s_waitcnt vmcnt(6)\n\ts_barrier" ::: "memory");
    }
    const char* bufA = (const char*)&smem[b][0];
    const char* bufB = bufA + (size_t)BM * 128;

    bf16x8 a0[AH][2], a1[AH][2], bf[4][2];
    // ---- P0: read A-half0 + B(0,1); MFMA A0 x B01 ----
#pragma unroll
    for (int i = 0; i < AH; ++i) {
      a0[i][0] = *(const bf16x8*)(bufA + baseA + i * 2048 + pOff0);
      a0[i][1] = *(const bf16x8*)(bufA + baseA + i * 2048 + pOff1);
    }
#pragma unroll
    for (int j = 0; j < 2; ++j) {
      bf[j][0] = *(const bf16x8*)(bufB + baseB + j * 2048 + pOff0);
      bf[j][1] = *(const bf16x8*)(bufB + baseB + j * 2048 + pOff1);
    }
    __builtin_amdgcn_s_setprio(1);
#pragma unroll
    for (int i = 0; i < AH; ++i)
#pragma unroll
      for (int j = 0; j < 2; ++j) {
        acc[i][j] = __builtin_amdgcn_mfma_f32_16x16x32_bf16(a0[i][0], bf[j][0], acc[i][j], 0, 0, 0);
        acc[i][j] = __builtin_amdgcn_mfma_f32_16x16x32_bf16(a0[i][1], bf[j][1], acc[i][j], 0, 0, 0);
      }
    __builtin_amdgcn_s_setprio(0);
    // ---- P1: read B(2,3); MFMA A0 x B23 ----
#pragma unroll
    for (int j = 2; j < 4; ++j) {
      bf[j][0] = *(const bf16x8*)(bufB + baseB + j * 2048 + pOff0);
      bf[j][1] = *(const bf16x8*)(bufB + baseB + j * 2048 + pOff1);
    }
    __builtin_amdgcn_s_setprio(1);
#pragma unroll
    for (int i = 0; i < AH; ++i)
#pragma unroll
      for (int j = 2; j < 4; ++j) {
        acc[i][j] = __builtin_amdgcn_mfma_f32_16x16x32_bf16(a0[i][0], bf[j][0], acc[i][j], 0, 0, 0);
        acc[i][j] = __builtin_amdgcn_mfma_f32_16x16x32_bf16(a0[i][1], bf[j][1], acc[i][j], 0, 0, 0);
      }
    __builtin_amdgcn_s_setprio(0);
    // ---- P2: read A-half1; MFMA A1 x B23 ----
#pragma unroll
    for (int i = 0; i < AH; ++i) {
      a1[i][0] = *(const bf16x8*)(bufA + baseA + (AH + i) * 2048 + pOff0);
      a1[i][1] = *(const bf16x8*)(bufA + baseA + (AH + i) * 2048 + pOff1);
    }
    __builtin_amdgcn_s_setprio(1);
#pragma unroll
    for (int i = 0; i < AH; ++i)
#pragma unroll
      for (int j = 2; j < 4; ++j) {
        acc[AH + i][j] = __builtin_amdgcn_mfma_f32_16x16x32_bf16(a1[i][0], bf[j][0], acc[AH + i][j], 0, 0, 0);
        acc[AH + i][j] = __builtin_amdgcn_mfma_f32_16x16x32_bf16(a1[i][1], bf[j][1], acc[AH + i][j], 0, 0, 0);
      }
    __builtin_amdgcn_s_setprio(0);
    // all my ds_reads of buf b retired; all waves synced -> buf b reusable
    asm volatile("s_waitcnt lgkmcnt(0)\n\ts_barrier" ::: "memory");
    if (t + 2 < NT) stage(t + 2, b);
    // ---- P3: MFMA A1 x B01 (overlaps staging issue) ----
    __builtin_amdgcn_s_setprio(1);
#pragma unroll
    for (int i = 0; i < AH; ++i)
#pragma unroll
      for (int j = 0; j < 2; ++j) {
        acc[AH + i][j] = __builtin_amdgcn_mfma_f32_16x16x32_bf16(a1[i][0], bf[j][0], acc[AH + i][j], 0, 0, 0);
        acc[AH + i][j] = __builtin_amdgcn_mfma_f32_16x16x32_bf16(a1[i][1], bf[j][1], acc[AH + i][j], 0, 0, 0);
      }
    __builtin_amdgcn_s_setprio(0);
  }

  // C/D layout (verified m89/m91): col = lane&15, row = quad*4 + reg
#pragma unroll
  for (int i = 0; i < IM; ++i)
#pragma unroll
    for (int j = 0; j < 4; ++j) {
      const int ccol = tileN + wn * 64 + j * 16 + r16;
#pragma unroll
      for (int rg = 0; rg < 4; ++rg) {
        const int rrow = tileM + wm * (BM / 2) + i * 16 + quad * 4 + rg;
        C[(size_t)rrow * N + ccol] = scale * acc[i][j][rg];
      }
    }
}

// ---------- fallback GEMM (small ws): manual staging, runtime dtype ----------
__global__ __launch_bounds__(256) void gemm_bt_f32(
    const void* __restrict__ Av, const void* __restrict__ Bv,
    const int* __restrict__ flag, float* __restrict__ C,
    int N, int K, float scale)
{
  __shared__ __align__(16) u16 As[128 * 32];
  __shared__ __align__(16) u16 Bs[128 * 32];
  const int tid  = threadIdx.x;
  const int lane = tid & 63;
  const int wave = tid >> 6;
  const int tileM = blockIdx.y * 128;
  const int tileN = blockIdx.x * 128;
  const int wm = (wave & 1) * 64;
  const int wn = (wave >> 1) * 64;
  const int quad = lane >> 4;
  const int r16  = lane & 15;
  const bool isBf16 = (*flag != 0);

  f32x4 acc[4][4] = {};

  for (int k0 = 0; k0 < K; k0 += 32) {
#pragma unroll
    for (int r = 0; r < 4; ++r) {
      const int idx = tid + 256 * r;
      const int row = idx >> 3;
      const int c   = (idx & 7) * 4;
      u16* da = &As[row * 32 + c];
      u16* db = &Bs[row * 32 + c];
      if (isBf16) {
        const u16* a16 = (const u16*)Av;
        const u16* b16 = (const u16*)Bv;
        *(ushort4*)da = *(const ushort4*)(a16 + (size_t)(tileM + row) * K + k0 + c);
        *(ushort4*)db = *(const ushort4*)(b16 + (size_t)(tileN + row) * K + k0 + c);
      } else {
        const float* a32 = (const float*)Av;
        const float* b32 = (const float*)Bv;
        const float4 va = *(const float4*)(a32 + (size_t)(tileM + row) * K + k0 + c);
        const float4 vb = *(const float4*)(b32 + (size_t)(tileN + row) * K + k0 + c);
        ushort4 pa, pb;
        pa.x = f32_to_bf16_bits(va.x); pa.y = f32_to_bf16_bits(va.y);
        pa.z = f32_to_bf16_bits(va.z); pa.w = f32_to_bf16_bits(va.w);
        pb.x = f32_to_bf16_bits(vb.x); pb.y = f32_to_bf16_bits(vb.y);
        pb.z = f32_to_bf16_bits(vb.z); pb.w = f32_to_bf16_bits(vb.w);
        *(ushort4*)da = pa;
        *(ushort4*)db = pb;
      }
    }
    __syncthreads();
    bf16x8 af[4], bfr[4];
#pragma unroll
    for (int i = 0; i < 4; ++i)
      af[i] = *(const bf16x8*)&As[(wm + i * 16 + r16) * 32 + quad * 8];
#pragma unroll
    for (int j = 0; j < 4; ++j)
      bfr[j] = *(const bf16x8*)&Bs[(wn + j * 16 + r16) * 32 + quad * 8];
#pragma unroll
    for (int i = 0; i < 4; ++i)
#pragma unroll
      for (int j = 0; j < 4; ++j)
        acc[i][j] = __builtin_amdgcn_mfma_f32_16x16x32_bf16(af[i], bfr[j], acc[i][j], 0, 0, 0);
    __syncthreads();
  }

#pragma unroll
  for (int i = 0; i < 4; ++i)
#pragma unroll
    for (int j = 0; j < 4; ++j) {
      const int ccol = tileN + wn + j * 16 + r16;
#pragma unroll
      for (int rg = 0; rg < 4; ++rg) {
        const int rrow = tileM + wm + i * 16 + quad * 4 + rg;
        C[(size_t)rrow * N + ccol] = scale * acc[i][j][rg];
      }
    }
}

// ---------- per-row class CE: lse(row) - row[class], float4 loads ----------
__global__ __launch_bounds__(256) void class_row(
    const float* __restrict__ scores, const int* __restrict__ classes,
    float* __restrict__ rlc)
{
  __shared__ float redf[4];
  const int b = blockIdx.x;
  const int tid = threadIdx.x;
  const float* row = scores + (size_t)b * Cn;
  float4 v[Cn / 1024];
#pragma unroll
  for (int s = 0; s < Cn / 1024; ++s)
    v[s] = *(const float4*)(row + s * 1024 + tid * 4);
  float m = -3.0e38f;
#pragma unroll
  for (int s = 0; s < Cn / 1024; ++s)
    m = fmaxf(m, fmaxf(fmaxf(v[s].x, v[s].y), fmaxf(v[s].z, v[s].w)));
  m = blk_max(m, redf);
  float sum = 0.f;
#pragma unroll
  for (int s = 0; s < Cn / 1024; ++s)
    sum += expf(v[s].x - m) + expf(v[s].y - m) + expf(v[s].z - m) + expf(v[s].w - m);
  sum = blk_sum(sum, redf);
  if (tid == 0) {
    const int cls = classes[b];
    rlc[b] = m + logf(sum) - row[cls];
  }
}

// ---------- per-row proxy loss: exact top-50 via key binary search ----------
__global__ __launch_bounds__(256) void proxy_row(
    const float* __restrict__ scores, const int* __restrict__ l2p,
    const int* __restrict__ labels, float* __restrict__ rlp)
{
  __shared__ float redf[4];
  __shared__ int redi[4];
  __shared__ int posIdx[Kp];
  __shared__ float posVal[Kp];
  const int b = blockIdx.x;
  const int tid = threadIdx.x;
  const float* row = scores + (size_t)b * Pn;

  if (tid < Kp) {
    const int lbl = labels[b];
    const int p = l2p[lbl * Kp + tid];
    posIdx[tid] = p;
    posVal[tid] = (p >= 0) ? row[p] : NEGV;   // gather BEFORE masking
  }
  __syncthreads();

  u64 excl = 0ull;
#pragma unroll
  for (int k = 0; k < Kp; ++k) {
    const int p = posIdx[k];
    if (p >= 0 && ((p >> 2) & 255) == tid)
      excl |= (1ull << (((p >> 10) << 2) | (p & 3)));
  }

  u32 key[Pn / 256];
  float vmax = -3.0e38f;
#pragma unroll
  for (int s = 0; s < Pn / 1024; ++s) {
    const float4 v4 = *(const float4*)(row + s * 1024 + tid * 4);
    const float vv[4] = {v4.x, v4.y, v4.z, v4.w};
#pragma unroll
    for (int j = 0; j < 4; ++j) {
      const float v = vv[j];
      const u32 bits = __float_as_uint(v);
      const u32 k = (bits & 0x80000000u) ? ~bits : (bits ^ 0x80000000u);
      const bool ex = (excl >> (s * 4 + j)) & 1ull;
      key[s * 4 + j] = ex ? 0u : k;            // key 0 = never selected
      if (!ex) vmax = fmaxf(vmax, v);
    }
  }
  float M = blk_max(vmax, redf);
#pragma unroll
  for (int k = 0; k < Kp; ++k) M = fmaxf(M, posVal[k]);

  // largest T with count(key >= T) >= 50  ->  T = 50th largest key
  u32 lo = 0;
  for (int bit = 31; bit >= 0; --bit) {
    const u32 cand = lo | (1u << bit);
    int c = 0;
#pragma unroll
    for (int s = 0; s < Pn / 256; ++s) c += (key[s] >= cand) ? 1 : 0;
    c = blk_sum_i(c, redi);
    if (c >= KNN) lo = cand;
  }

  int cgt = 0; float s1 = 0.f;
#pragma unroll
  for (int s = 0; s < Pn / 256; ++s) {
    if (key[s] > lo) {
      ++cgt;
      const u32 kk = key[s];
      const u32 bits = (kk & 0x80000000u) ? (kk ^ 0x80000000u) : ~kk;
      s1 += expf(__uint_as_float(bits) - M);
    }
  }
  cgt = blk_sum_i(cgt, redi);
  s1 = blk_sum(s1, redf);

  if (tid == 0) {
    const u32 tb = (lo & 0x80000000u) ? (lo ^ 0x80000000u) : ~lo;
    const float tv = __uint_as_float(tb);
    const float Sneg = s1 + (float)(KNN - cgt) * expf(tv - M);
    float Spos = 0.f, sp = 0.f; int nv = 0;
#pragma unroll
    for (int k = 0; k < Kp; ++k) {
      Spos += expf(posVal[k] - M);
      if (posIdx[k] >= 0) { sp += posVal[k]; ++nv; }
    }
    float loss = 0.f;
    if (nv > 0) loss = M + logf(Spos + Sneg) - sp / (float)nv;
    rlp[b] = loss;
  }
}

// ---------- final: mean over batch, fp32 store ----------
__global__ __launch_bounds__(256) void final_reduce(
    const float* __restrict__ rlp, const float* __restrict__ rlc,
    float* __restrict__ out)
{
  __shared__ float redf[4];
  const int tid = threadIdx.x;
  float acc = 0.f;
  for (int i = tid; i < Bn; i += 256) acc += rlp[i] + rlc[i];
  acc = blk_sum(acc, redf);
  if (tid == 0) out[0] = acc * (1.0f / (float)Bn);
}

extern "C" void kernel_launch(void* const* d_in, const int* in_sizes, int n_in,
                              void* d_out, int out_size, void* d_ws, size_t ws_size,
                              hipStream_t stream) {
  const void* inputs  = d_in[0];              // [B,D]  float (fp32-holding-bf16 or bf16)
  const void* pcent   = d_in[1];              // [P,D]
  const void* ccent   = d_in[2];              // [C,D]
  const int* l2p      = (const int*)d_in[3];  // [C,K]
  const int* labels   = (const int*)d_in[5];  // [B]
  const int* classes  = (const int*)d_in[6];  // [B]

  char* ws = (char*)d_ws;
  float* scores = (float*)ws;                                  // 64 MB
  size_t off = (size_t)64 * 1024 * 1024;
  float* rlc = (float*)(ws + off);  off += Bn * 4;
  float* rlp = (float*)(ws + off);  off += Bn * 4;
  int* flag  = (int*)(ws + off);    off += 4096;               // pad
  u16* Abf   = (u16*)(ws + off);    off += (size_t)Bn * Dn * 2;
  u16* Cbf   = (u16*)(ws + off);    off += (size_t)Cn * Dn * 2;
  u16* Pbf   = (u16*)(ws + off);    off += (size_t)Pn * Dn * 2;
  const bool big = (ws_size >= off);          // constant per-run -> graph-safe

  sniff<<<1, 256, 0, stream>>>(inputs, flag);

  if (big) {
    to_bf16_all<<<4096, 256, 0, stream>>>(inputs, ccent, pcent, Abf, Cbf, Pbf, flag);

    // class GEMM: BM=128 -> grid 32x8 = 256 blocks
    gemm_4ph<128><<<dim3(Cn / 256, Bn / 128), 512, 0, stream>>>(
        Abf, Cbf, scores, Cn, INV_TEMP);
    class_row<<<Bn, 256, 0, stream>>>(scores, classes, rlc);

    // proxy GEMM: BM=256 -> grid 64x4 = 256 blocks, 1/CU
    gemm_4ph<256><<<dim3(Pn / 256, Bn / 256), 512, 0, stream>>>(
        Abf, Pbf, scores, Pn, INV_TEMP);
    proxy_row<<<Bn, 256, 0, stream>>>(scores, l2p, labels, rlp);
  } else {
    gemm_bt_f32<<<dim3(Cn / 128, Bn / 128), 256, 0, stream>>>(
        inputs, ccent, flag, scores, Cn, Dn, INV_TEMP);
    class_row<<<Bn, 256, 0, stream>>>(scores, classes, rlc);

    gemm_bt_f32<<<dim3(Pn / 128, Bn / 128), 256, 0, stream>>>(
        inputs, pcent, flag, scores, Pn, Dn, INV_TEMP);
    proxy_row<<<Bn, 256, 0, stream>>>(scores, l2p, labels, rlp);
  }

  final_reduce<<<1, 256, 0, stream>>>(rlp, rlc, (float*)d_out);
}